// Round 7
// baseline (239.776 us; speedup 1.0000x reference)
//
#include <hip/hip_runtime.h>
#include <math.h>

// Problem constants (from setup_inputs): local_f [4608,4096] f32,
// text_embedding [128,4096] f32, attn_mask [128] (int per harness), gumbel [4608] f32.
#define NIMG 4608
#define NTXT 128
#define DD   4096
#define DD4  1024   // DD/4
#define EPSF 1e-8f
#define TOPPF 0.9f  // fp32(0.9) — numpy compares fp32 array vs weak python float -> fp32

// Copy-share row boundaries: the 75.5 MB local_f->out copy is spread across the
// three serial-tail dispatches so it overlaps softmax / rank / cumsum.
#define CP1_END 2048   // rows [0,2048)    copied during softmax  (512 blocks x 4 rows)
#define CP2_END 2560   // rows [2048,2560) copied during rank     (512 blocks x 1 row)
                        // rows [2560,4608) copied during cumsum  (2048 blocks x 1 row)

// ---------- block reduce helpers (1024 threads, 16 waves) ----------
__device__ __forceinline__ float bredmax(float v, float* red) {
#pragma unroll
  for (int o = 32; o; o >>= 1) v = fmaxf(v, __shfl_down(v, o));
  int w = threadIdx.x >> 6, l = threadIdx.x & 63;
  __syncthreads();                // protect red[] from previous use
  if (l == 0) red[w] = v;
  __syncthreads();
  if (threadIdx.x == 0) {
    float m = red[0];
#pragma unroll
    for (int i = 1; i < 16; ++i) m = fmaxf(m, red[i]);
    red[0] = m;
  }
  __syncthreads();
  return red[0];
}

__device__ __forceinline__ float bredsum(float v, float* red) {
#pragma unroll
  for (int o = 32; o; o >>= 1) v += __shfl_down(v, o);
  int w = threadIdx.x >> 6, l = threadIdx.x & 63;
  __syncthreads();
  if (l == 0) red[w] = v;
  __syncthreads();
  if (threadIdx.x == 0) {
    float s = red[0];
#pragma unroll
    for (int i = 1; i < 16; ++i) s += red[i];
    red[0] = s;
  }
  __syncthreads();
  return red[0];
}

// ---------- K1: fused text-norm + v-vector (replaces k_txt -> k_v) ----------
// Each of 16 blocks REDUNDANTLY computes all 128 masked reciprocal norms
// (2 MB re-read, L2-served after first block) with the BITWISE-IDENTICAL
// wave pattern of the old k_txt (64-lane stride-64 float4 accumulation +
// same shfl_down chain), stages them in LDS, then computes its 256 columns
// of v[d] = sum_j txt[j][d] * rtxt[j] in the old k_v's exact j-order.
// No cross-block dependency -> one dispatch, no global rtxt.
__global__ __launch_bounds__(256) void k_tv(const float4* __restrict__ txt4,
                                            const float* __restrict__ txt,
                                            const int* __restrict__ mask,
                                            float* __restrict__ vout) {
  __shared__ float rt[NTXT];
  int tid = threadIdx.x, wave = tid >> 6, lane = tid & 63;
  // ---- norms: wave w handles rows w, w+4, ... (same per-row arithmetic) ----
  for (int row = wave; row < NTXT; row += 4) {
    const float4* p = txt4 + row * DD4;
    float ss = 0.f;
#pragma unroll
    for (int t = 0; t < DD4; t += 64) {
      float4 a = p[t + lane];
      ss = fmaf(a.x, a.x, ss); ss = fmaf(a.y, a.y, ss);
      ss = fmaf(a.z, a.z, ss); ss = fmaf(a.w, a.w, ss);
    }
#pragma unroll
    for (int o = 32; o; o >>= 1) ss += __shfl_down(ss, o);
    if (lane == 0) {
      float n = fmaxf(sqrtf(ss), EPSF);
      rt[row] = mask[row] ? (1.0f / n) : 0.0f;
    }
  }
  __syncthreads();
  // ---- v-columns: identical j-ascending fmaf chain to old k_v ----
  int d = blockIdx.x * 256 + tid;   // 16 blocks x 256 = 4096
  float acc = 0.f;
#pragma unroll 4
  for (int j = 0; j < NTXT; ++j) acc = fmaf(txt[j * DD + d], rt[j], acc);
  vout[d] = acc;
}

// ---------- K3: per-image-row sim_sum[i] = (f_i . v)/max(||f_i||,EPS) ----------
// Pure-read kernel (dot + self-norm only); read-BW bound, so no writes here.
// one wave per row, 4 waves/block
__global__ void k_img(const float4* __restrict__ f, const float4* __restrict__ v,
                      float* __restrict__ simsum) {
  int wave = threadIdx.x >> 6, lane = threadIdx.x & 63;
  int row = blockIdx.x * 4 + wave;
  const float4* p = f + row * DD4;
  float d0 = 0.f, d1 = 0.f, s0 = 0.f, s1 = 0.f;
#pragma unroll
  for (int t = 0; t < DD4; t += 64) {
    float4 a = p[t + lane];
    float4 b = v[t + lane];
    d0 = fmaf(a.x, b.x, d0); d1 = fmaf(a.y, b.y, d1);
    d0 = fmaf(a.z, b.z, d0); d1 = fmaf(a.w, b.w, d1);
    s0 = fmaf(a.x, a.x, s0); s1 = fmaf(a.y, a.y, s1);
    s0 = fmaf(a.z, a.z, s0); s1 = fmaf(a.w, a.w, s1);
  }
  float dot = d0 + d1, ss = s0 + s1;
#pragma unroll
  for (int o = 32; o; o >>= 1) { dot += __shfl_down(dot, o); ss += __shfl_down(ss, o); }
  if (lane == 0) simsum[row] = dot / fmaxf(sqrtf(ss), EPSF);
}

// ---------- K4: block 0 = serial softmax chain; blocks 1..512 copy rows [0,2048) ----------
__global__ __launch_bounds__(1024) void k_smcopy(const float* __restrict__ simsum,
                                                 const float* __restrict__ gumbel,
                                                 float* __restrict__ probs2,
                                                 int* __restrict__ ranks,
                                                 const float4* __restrict__ f,
                                                 float4* __restrict__ out) {
  __shared__ float xs[NIMG];
  __shared__ float red[16];
  int tid = threadIdx.x;

  if (blockIdx.x != 0) {
    // ---- copy role: 512 blocks x 4 rows, 4 waves per row ----
    int blk = blockIdx.x - 1;                 // 0..511
    int wave = tid >> 6, lane = tid & 63;
    int row = blk * 4 + (wave >> 2);          // rows [0, 2048)
    int seg = (wave & 3) * 256;               // quarter-row of float4s
    const float4* p = f + row * DD4 + seg;
    float4* q = out + row * DD4 + seg;
#pragma unroll
    for (int t = 0; t < 256; t += 64) q[t + lane] = p[t + lane];
    return;
  }

  // ---- softmax role (identical arithmetic to the original) ----
  float mymax = -INFINITY;
  for (int i = tid; i < NIMG; i += 1024) {
    float x = simsum[i] * 2.0f;   // /0.5 == *2 exactly
    xs[i] = x;
    mymax = fmaxf(mymax, x);
  }
  float m1 = bredmax(mymax, red);

  float mysum = 0.f;
  for (int i = tid; i < NIMG; i += 1024) {
    float e = expf(xs[i] - m1);
    xs[i] = e;
    mysum += e;
  }
  float s1 = bredsum(mysum, red);

  mymax = -INFINITY;
  for (int i = tid; i < NIMG; i += 1024) {
    float z = xs[i] / s1 + gumbel[i];   // probs1 + noise
    xs[i] = z;
    mymax = fmaxf(mymax, z);
  }
  float m2 = bredmax(mymax, red);

  mysum = 0.f;
  for (int i = tid; i < NIMG; i += 1024) {
    float e = expf(xs[i] - m2);
    xs[i] = e;
    mysum += e;
  }
  float s2 = bredsum(mysum, red);

  for (int i = tid; i < NIMG; i += 1024) {
    probs2[i] = xs[i] / s2;
    ranks[i] = 0;                 // ws is poisoned each call — re-init here
  }
}

// ---------- K5: rank (blocks 0..287) + copy rows [2048,2560) (blocks 288..799) ----------
// rank_i = #{ j : p_j > p_i  or (p_j == p_i and j < i) }  (ranks unique)
#define JCHUNK 288
__global__ __launch_bounds__(256) void k_rankcopy(const float* __restrict__ probs,
                                                  int* __restrict__ ranks,
                                                  const float4* __restrict__ f,
                                                  float4* __restrict__ out) {
  __shared__ float pj[JCHUNK];
  if (blockIdx.x >= 288) {
    // ---- copy role: one row per block, 256 threads ----
    int row = CP1_END + (blockIdx.x - 288);   // rows [2048, 2560)
    const float4* p = f + row * DD4;
    float4* q = out + row * DD4;
#pragma unroll
    for (int t = 0; t < DD4; t += 256) q[t + threadIdx.x] = p[t + threadIdx.x];
    return;
  }
  int bx = blockIdx.x % 18, by = blockIdx.x / 18;  // 18 x 16 as before
  int i = bx * 256 + threadIdx.x;           // 18*256 = 4608 exactly
  int jbase = by * JCHUNK;                  // 16*288 = 4608 exactly
  for (int t = threadIdx.x; t < JCHUNK; t += 256) pj[t] = probs[jbase + t];
  __syncthreads();
  float pi = probs[i];
  int tielim = i - jbase;                   // t < tielim  <=>  j < i
  int cnt = 0;
#pragma unroll 4
  for (int t = 0; t < JCHUNK; ++t) {
    float p = pj[t];
    cnt += (int)((p > pi) || ((p == pi) && (t < tielim)));
  }
  atomicAdd(&ranks[i], cnt);
}

// ---------- K6: cumsum (block 0) + copy rows [2560,4608) (blocks 1..2048) ----------
// Pass A: one wave walks the full chain sequentially (matches np.cumsum bitwise),
// snapshotting the running sum at every 64-element chunk boundary.
// Pass B: each thread resumes from its chunk's exact snapshot -> identical partials,
// counts cum <= 0.9 in parallel. k = min(count+1, N).
__global__ __launch_bounds__(256) void k_cumsumcopy(const float* __restrict__ probs,
                                                    const int* __restrict__ ranks,
                                                    int* __restrict__ kout,
                                                    const float4* __restrict__ f,
                                                    float4* __restrict__ out) {
  __shared__ float sorted[NIMG];
  __shared__ float snap[NIMG / 64];
  __shared__ int cnt_s;
  int tid = threadIdx.x;

  if (blockIdx.x != 0) {
    // ---- copy role: one row per block, 256 threads ----
    int row = CP2_END + (blockIdx.x - 1);    // rows [2560, 4608)
    const float4* p = f + row * DD4;
    float4* q = out + row * DD4;
#pragma unroll
    for (int t = 0; t < DD4; t += 256) q[t + tid] = p[t + tid];
    return;
  }

  for (int i = tid; i < NIMG; i += 256) sorted[ranks[i]] = probs[i];
  if (tid == 0) cnt_s = 0;
  __syncthreads();

  if (tid < 64) {                       // all lanes redundantly compute same chain
    float cum = 0.f;
    for (int c = 0; c < NIMG / 64; ++c) {
      snap[c] = cum;                    // same value from all lanes — benign
      const float4* s4 = (const float4*)(sorted + c * 64);
#pragma unroll
      for (int t = 0; t < 16; ++t) {
        float4 q = s4[t];
        cum += q.x; cum += q.y; cum += q.z; cum += q.w;   // strict sequential order
      }
    }
  }
  __syncthreads();

  if (tid < NIMG / 64) {
    float cum = snap[tid];
    int cnt = 0;
    const float4* s4 = (const float4*)(sorted + tid * 64);
#pragma unroll
    for (int t = 0; t < 16; ++t) {
      float4 q = s4[t];
      cum += q.x; cnt += (int)(cum <= TOPPF);
      cum += q.y; cnt += (int)(cum <= TOPPF);
      cum += q.z; cnt += (int)(cum <= TOPPF);
      cum += q.w; cnt += (int)(cum <= TOPPF);
    }
    atomicAdd(&cnt_s, cnt);
  }
  __syncthreads();
  if (tid == 0) {
    int k = cnt_s + 1;
    if (k > NIMG) k = NIMG;
    *kout = k;
  }
}

// ---------- K7: zero only the dropped rows (rank >= k), ~10% of rows ----------
// out already holds a verbatim copy of local_f (written across K4/K5/K6).
__global__ __launch_bounds__(256) void k_zero(const int* __restrict__ ranks,
                                              const int* __restrict__ kout,
                                              float4* __restrict__ out) {
  const int k = *kout;
  int wave = threadIdx.x >> 6, lane = threadIdx.x & 63;
  int base = blockIdx.x * 16 + wave * 4;    // 288 blocks x 16 rows = 4608
  float4 z; z.x = 0.f; z.y = 0.f; z.z = 0.f; z.w = 0.f;
  for (int r = 0; r < 4; ++r) {
    int row = base + r;
    if (ranks[row] >= k) {
      float4* q = out + row * DD4;
#pragma unroll
      for (int t = 0; t < DD4; t += 64) q[t + lane] = z;
    }
  }
}

extern "C" void kernel_launch(void* const* d_in, const int* in_sizes, int n_in,
                              void* d_out, int out_size, void* d_ws, size_t ws_size,
                              hipStream_t stream) {
  const float* local_f = (const float*)d_in[0];
  const float* text    = (const float*)d_in[1];
  const int*   mask    = (const int*)d_in[2];   // bool -> int per harness convention
  const float* gumbel  = (const float*)d_in[3];
  float* out = (float*)d_out;

  // ws layout (floats); total ~74 KB
  float* ws     = (float*)d_ws;
  float* simsum = ws;                   // [4608]
  float* probs2 = ws + 4608;            // [4608]
  int*   ranks  = (int*)(ws + 9216);    // [4608]
  int*   kout   = (int*)(ws + 13824);   // [1]
  float* vvec   = ws + 14336;           // [4096], 16B-aligned offset

  k_tv        <<<DD / 256, 256, 0, stream>>>((const float4*)text, text, mask, vvec);
  k_img       <<<NIMG / 4, 256, 0, stream>>>((const float4*)local_f, (const float4*)vvec, simsum);
  k_smcopy    <<<1 + CP1_END / 4, 1024, 0, stream>>>(simsum, gumbel, probs2, ranks,
                                                     (const float4*)local_f, (float4*)out);
  k_rankcopy  <<<288 + (CP2_END - CP1_END), 256, 0, stream>>>(probs2, ranks,
                                                              (const float4*)local_f, (float4*)out);
  k_cumsumcopy<<<1 + (NIMG - CP2_END), 256, 0, stream>>>(probs2, ranks, kout,
                                                         (const float4*)local_f, (float4*)out);
  k_zero      <<<288, 256, 0, stream>>>(ranks, kout, (float4*)out);
}

// Round 8
// 191.987 us; speedup vs baseline: 1.2489x; 1.2489x over previous
//
#include <hip/hip_runtime.h>
#include <math.h>

// Problem constants (from setup_inputs): local_f [4608,4096] f32,
// text_embedding [128,4096] f32, attn_mask [128] (int per harness), gumbel [4608] f32.
#define NIMG 4608
#define NTXT 128
#define DD   4096
#define DD4  1024   // DD/4
#define EPSF 1e-8f
#define TOPPF 0.9f  // fp32(0.9) — numpy compares fp32 array vs weak python float -> fp32

// Copy-share row boundaries: the 75.5 MB local_f->out copy is spread across the
// three serial-tail dispatches so it overlaps softmax / rank / cumsum.
#define CP1_END 2048   // rows [0,2048)    copied during softmax  (512 blocks x 4 rows)
#define CP2_END 2560   // rows [2048,2560) copied during rank     (512 blocks x 1 row)
                        // rows [2560,4608) copied during cumsum  (2048 blocks x 1 row)

// ---------- block reduce helpers (1024 threads, 16 waves) ----------
__device__ __forceinline__ float bredmax(float v, float* red) {
#pragma unroll
  for (int o = 32; o; o >>= 1) v = fmaxf(v, __shfl_down(v, o));
  int w = threadIdx.x >> 6, l = threadIdx.x & 63;
  __syncthreads();                // protect red[] from previous use
  if (l == 0) red[w] = v;
  __syncthreads();
  if (threadIdx.x == 0) {
    float m = red[0];
#pragma unroll
    for (int i = 1; i < 16; ++i) m = fmaxf(m, red[i]);
    red[0] = m;
  }
  __syncthreads();
  return red[0];
}

__device__ __forceinline__ float bredsum(float v, float* red) {
#pragma unroll
  for (int o = 32; o; o >>= 1) v += __shfl_down(v, o);
  int w = threadIdx.x >> 6, l = threadIdx.x & 63;
  __syncthreads();
  if (l == 0) red[w] = v;
  __syncthreads();
  if (threadIdx.x == 0) {
    float s = red[0];
#pragma unroll
    for (int i = 1; i < 16; ++i) s += red[i];
    red[0] = s;
  }
  __syncthreads();
  return red[0];
}

// ---------- K1: per-text-row norm -> masked reciprocal ----------
// rtxt[j] = mask[j] ? 1/max(||t_j||, EPS) : 0
__global__ void k_txt(const float4* __restrict__ txt, const int* __restrict__ mask,
                      float* __restrict__ rtxt) {
  int row = blockIdx.x, lane = threadIdx.x;  // 128 blocks x 64
  const float4* p = txt + row * DD4;
  float ss = 0.f;
#pragma unroll
  for (int t = 0; t < DD4; t += 64) {
    float4 a = p[t + lane];
    ss = fmaf(a.x, a.x, ss); ss = fmaf(a.y, a.y, ss);
    ss = fmaf(a.z, a.z, ss); ss = fmaf(a.w, a.w, ss);
  }
#pragma unroll
  for (int o = 32; o; o >>= 1) ss += __shfl_down(ss, o);
  if (lane == 0) {
    float n = fmaxf(sqrtf(ss), EPSF);
    rtxt[row] = mask[row] ? (1.0f / n) : 0.0f;
  }
}

// ---------- K2: v[d] = sum_j txt[j][d] * rtxt[j] ----------
__global__ void k_v(const float* __restrict__ txt, const float* __restrict__ rtxt,
                    float* __restrict__ vout) {
  int d = blockIdx.x * 256 + threadIdx.x;  // 16 blocks x 256 = 4096
  float acc = 0.f;
#pragma unroll 4
  for (int j = 0; j < NTXT; ++j) acc = fmaf(txt[j * DD + d], rtxt[j], acc);
  vout[d] = acc;
}

// ---------- K3: per-image-row sim_sum[i] = (f_i . v)/max(||f_i||,EPS) ----------
// Pure-read kernel (dot + self-norm only); read-BW bound, so no writes here.
// one wave per row, 4 waves/block
__global__ void k_img(const float4* __restrict__ f, const float4* __restrict__ v,
                      float* __restrict__ simsum) {
  int wave = threadIdx.x >> 6, lane = threadIdx.x & 63;
  int row = blockIdx.x * 4 + wave;
  const float4* p = f + row * DD4;
  float d0 = 0.f, d1 = 0.f, s0 = 0.f, s1 = 0.f;
#pragma unroll
  for (int t = 0; t < DD4; t += 64) {
    float4 a = p[t + lane];
    float4 b = v[t + lane];
    d0 = fmaf(a.x, b.x, d0); d1 = fmaf(a.y, b.y, d1);
    d0 = fmaf(a.z, b.z, d0); d1 = fmaf(a.w, b.w, d1);
    s0 = fmaf(a.x, a.x, s0); s1 = fmaf(a.y, a.y, s1);
    s0 = fmaf(a.z, a.z, s0); s1 = fmaf(a.w, a.w, s1);
  }
  float dot = d0 + d1, ss = s0 + s1;
#pragma unroll
  for (int o = 32; o; o >>= 1) { dot += __shfl_down(dot, o); ss += __shfl_down(ss, o); }
  if (lane == 0) simsum[row] = dot / fmaxf(sqrtf(ss), EPSF);
}

// ---------- K4: block 0 = serial softmax chain; blocks 1..512 copy rows [0,2048) ----------
__global__ __launch_bounds__(1024) void k_smcopy(const float* __restrict__ simsum,
                                                 const float* __restrict__ gumbel,
                                                 float* __restrict__ probs2,
                                                 int* __restrict__ ranks,
                                                 const float4* __restrict__ f,
                                                 float4* __restrict__ out) {
  __shared__ float xs[NIMG];
  __shared__ float red[16];
  int tid = threadIdx.x;

  if (blockIdx.x != 0) {
    // ---- copy role: 512 blocks x 4 rows, 4 waves per row ----
    int blk = blockIdx.x - 1;                 // 0..511
    int wave = tid >> 6, lane = tid & 63;
    int row = blk * 4 + (wave >> 2);          // rows [0, 2048)
    int seg = (wave & 3) * 256;               // quarter-row of float4s
    const float4* p = f + row * DD4 + seg;
    float4* q = out + row * DD4 + seg;
#pragma unroll
    for (int t = 0; t < 256; t += 64) q[t + lane] = p[t + lane];
    return;
  }

  // ---- softmax role (identical arithmetic to the original) ----
  float mymax = -INFINITY;
  for (int i = tid; i < NIMG; i += 1024) {
    float x = simsum[i] * 2.0f;   // /0.5 == *2 exactly
    xs[i] = x;
    mymax = fmaxf(mymax, x);
  }
  float m1 = bredmax(mymax, red);

  float mysum = 0.f;
  for (int i = tid; i < NIMG; i += 1024) {
    float e = expf(xs[i] - m1);
    xs[i] = e;
    mysum += e;
  }
  float s1 = bredsum(mysum, red);

  mymax = -INFINITY;
  for (int i = tid; i < NIMG; i += 1024) {
    float z = xs[i] / s1 + gumbel[i];   // probs1 + noise
    xs[i] = z;
    mymax = fmaxf(mymax, z);
  }
  float m2 = bredmax(mymax, red);

  mysum = 0.f;
  for (int i = tid; i < NIMG; i += 1024) {
    float e = expf(xs[i] - m2);
    xs[i] = e;
    mysum += e;
  }
  float s2 = bredsum(mysum, red);

  for (int i = tid; i < NIMG; i += 1024) {
    probs2[i] = xs[i] / s2;
    ranks[i] = 0;                 // ws is poisoned each call — re-init here
  }
}

// ---------- K5: rank (blocks 0..287) + copy rows [2048,2560) (blocks 288..799) ----------
// rank_i = #{ j : p_j > p_i  or (p_j == p_i and j < i) }  (ranks unique)
#define JCHUNK 288
__global__ __launch_bounds__(256) void k_rankcopy(const float* __restrict__ probs,
                                                  int* __restrict__ ranks,
                                                  const float4* __restrict__ f,
                                                  float4* __restrict__ out) {
  __shared__ float pj[JCHUNK];
  if (blockIdx.x >= 288) {
    // ---- copy role: one row per block, 256 threads ----
    int row = CP1_END + (blockIdx.x - 288);   // rows [2048, 2560)
    const float4* p = f + row * DD4;
    float4* q = out + row * DD4;
#pragma unroll
    for (int t = 0; t < DD4; t += 256) q[t + threadIdx.x] = p[t + threadIdx.x];
    return;
  }
  int bx = blockIdx.x % 18, by = blockIdx.x / 18;  // 18 x 16 as before
  int i = bx * 256 + threadIdx.x;           // 18*256 = 4608 exactly
  int jbase = by * JCHUNK;                  // 16*288 = 4608 exactly
  for (int t = threadIdx.x; t < JCHUNK; t += 256) pj[t] = probs[jbase + t];
  __syncthreads();
  float pi = probs[i];
  int tielim = i - jbase;                   // t < tielim  <=>  j < i
  int cnt = 0;
#pragma unroll 4
  for (int t = 0; t < JCHUNK; ++t) {
    float p = pj[t];
    cnt += (int)((p > pi) || ((p == pi) && (t < tielim)));
  }
  atomicAdd(&ranks[i], cnt);
}

// ---------- K6: cumsum (block 0) + copy rows [2560,4608) (blocks 1..2048) ----------
// Pass A: one wave walks the full chain sequentially (matches np.cumsum bitwise),
// snapshotting the running sum at every 64-element chunk boundary.
// Pass B: each thread resumes from its chunk's exact snapshot -> identical partials,
// counts cum <= 0.9 in parallel. k = min(count+1, N).
__global__ __launch_bounds__(256) void k_cumsumcopy(const float* __restrict__ probs,
                                                    const int* __restrict__ ranks,
                                                    int* __restrict__ kout,
                                                    const float4* __restrict__ f,
                                                    float4* __restrict__ out) {
  __shared__ float sorted[NIMG];
  __shared__ float snap[NIMG / 64];
  __shared__ int cnt_s;
  int tid = threadIdx.x;

  if (blockIdx.x != 0) {
    // ---- copy role: one row per block, 256 threads ----
    int row = CP2_END + (blockIdx.x - 1);    // rows [2560, 4608)
    const float4* p = f + row * DD4;
    float4* q = out + row * DD4;
#pragma unroll
    for (int t = 0; t < DD4; t += 256) q[t + tid] = p[t + tid];
    return;
  }

  for (int i = tid; i < NIMG; i += 256) sorted[ranks[i]] = probs[i];
  if (tid == 0) cnt_s = 0;
  __syncthreads();

  if (tid < 64) {                       // all lanes redundantly compute same chain
    float cum = 0.f;
    for (int c = 0; c < NIMG / 64; ++c) {
      snap[c] = cum;                    // same value from all lanes — benign
      const float4* s4 = (const float4*)(sorted + c * 64);
#pragma unroll
      for (int t = 0; t < 16; ++t) {
        float4 q = s4[t];
        cum += q.x; cum += q.y; cum += q.z; cum += q.w;   // strict sequential order
      }
    }
  }
  __syncthreads();

  if (tid < NIMG / 64) {
    float cum = snap[tid];
    int cnt = 0;
    const float4* s4 = (const float4*)(sorted + tid * 64);
#pragma unroll
    for (int t = 0; t < 16; ++t) {
      float4 q = s4[t];
      cum += q.x; cnt += (int)(cum <= TOPPF);
      cum += q.y; cnt += (int)(cum <= TOPPF);
      cum += q.z; cnt += (int)(cum <= TOPPF);
      cum += q.w; cnt += (int)(cum <= TOPPF);
    }
    atomicAdd(&cnt_s, cnt);
  }
  __syncthreads();
  if (tid == 0) {
    int k = cnt_s + 1;
    if (k > NIMG) k = NIMG;
    *kout = k;
  }
}

// ---------- K7: zero only the dropped rows (rank >= k), ~10% of rows ----------
// out already holds a verbatim copy of local_f (written across K4/K5/K6).
__global__ __launch_bounds__(256) void k_zero(const int* __restrict__ ranks,
                                              const int* __restrict__ kout,
                                              float4* __restrict__ out) {
  const int k = *kout;
  int wave = threadIdx.x >> 6, lane = threadIdx.x & 63;
  int base = blockIdx.x * 16 + wave * 4;    // 288 blocks x 16 rows = 4608
  float4 z; z.x = 0.f; z.y = 0.f; z.z = 0.f; z.w = 0.f;
  for (int r = 0; r < 4; ++r) {
    int row = base + r;
    if (ranks[row] >= k) {
      float4* q = out + row * DD4;
#pragma unroll
      for (int t = 0; t < DD4; t += 64) q[t + lane] = z;
    }
  }
}

extern "C" void kernel_launch(void* const* d_in, const int* in_sizes, int n_in,
                              void* d_out, int out_size, void* d_ws, size_t ws_size,
                              hipStream_t stream) {
  const float* local_f = (const float*)d_in[0];
  const float* text    = (const float*)d_in[1];
  const int*   mask    = (const int*)d_in[2];   // bool -> int per harness convention
  const float* gumbel  = (const float*)d_in[3];
  float* out = (float*)d_out;

  // ws layout (floats); total ~74 KB
  float* ws     = (float*)d_ws;
  float* simsum = ws;                   // [4608]
  float* probs2 = ws + 4608;            // [4608]
  int*   ranks  = (int*)(ws + 9216);    // [4608]
  int*   kout   = (int*)(ws + 13824);   // [1]
  float* rtxt   = ws + 13828;           // [128]
  float* vvec   = ws + 14336;           // [4096], 16B-aligned offset

  k_txt       <<<NTXT, 64, 0, stream>>>((const float4*)text, mask, rtxt);
  k_v         <<<DD / 256, 256, 0, stream>>>(text, rtxt, vvec);
  k_img       <<<NIMG / 4, 256, 0, stream>>>((const float4*)local_f, (const float4*)vvec, simsum);
  k_smcopy    <<<1 + CP1_END / 4, 1024, 0, stream>>>(simsum, gumbel, probs2, ranks,
                                                     (const float4*)local_f, (float4*)out);
  k_rankcopy  <<<288 + (CP2_END - CP1_END), 256, 0, stream>>>(probs2, ranks,
                                                              (const float4*)local_f, (float4*)out);
  k_cumsumcopy<<<1 + (NIMG - CP2_END), 256, 0, stream>>>(probs2, ranks, kout,
                                                         (const float4*)local_f, (float4*)out);
  k_zero      <<<288, 256, 0, stream>>>(ranks, kout, (float4*)out);
}